// Round 9
// baseline (372.607 us; speedup 1.0000x reference)
//
#include <hip/hip_runtime.h>
#include <hip/hip_bf16.h>

// Net_22625887715641: fused conv-feats + channel-normalize + 32x32 normalized
// cross-correlation (23x23 shifts, 362x362 templates).
//
// R9 vs R8 (corr 214us, MfmaUtil 33%, LDS/MFMA co-bound at 3 waves/SIMD):
//  - corr switched to fp8 e4m3 MFMA (16x16x32_fp8_fp8): halves LDS bytes/FLOP
//    (B frag = one ds_read_b64) and operand regs (48->24 VGPR) -> ~120 regs
//    -> 4 waves/SIMD via __launch_bounds__(256,4); grid 1024 = 4 blocks/CU.
//  - B staging halves: 104 tasks/y build 8 byte-shifted copies (432B stride,
//    16B-aligned b128 writes, 48B bank stagger) from one 24B window each.
//  - filtb/prevb packed e4m3 by pack_kernel/feat (hand-rolled RNE encoder).
//  - Precision: e4m3 worst-case x2 err ~1.5e-4 << 1.37e-2 threshold; absmax
//    is x1-dominated (fp32 path unchanged).

typedef unsigned short ushort_t;
typedef unsigned int uint_t;
typedef unsigned char uchar_t;
typedef __attribute__((ext_vector_type(4))) float f32x4;
typedef __attribute__((ext_vector_type(4))) uint_t uint4_t;
typedef __attribute__((ext_vector_type(2))) uint_t uint2_t;

#define EPSF 2.2204460492503131e-16f
#define X1_N (32*384*384)
#define X2_N (32*32*23*23)

// filtb: fp8 [372 rows][48 xb][32 o][8 j]; row = yf+5 (data rows 5..366)
#define FILTB_BYTES (372*48*32*8)
// prevb: fp8 [32 c][385 rows][432 x]; data rows 0..383 cols 0..383; zeros else
#define PREVB_STRIDE 432
#define PREVB_BYTES (32*385*PREVB_STRIDE)
#define ZERO_BYTES ((size_t)FILTB_BYTES + PREVB_BYTES)
// fT2: fp32 [16 chp][45 rows][12] after prevb
#define FT2_ELEMS (16*45*12)

#define YMAX 367            // y-steps 0..366
#define NCHUNKS 32          // balanced: chunk c covers [c*367/32,(c+1)*367/32)
#define INV_AREA (1.0f/131044.0f)

// sB bytes: [dyb 4][copy 8][432]; copy stride 432 (16-mult, 48B bank stagger)
#define SB_COPY_B 432
#define SB_DYB_B  (8*SB_COPY_B)     // 3456
#define SB_BYTES  (4*SB_DYB_B)      // 13824 -> 4 blocks/CU = 55.3KB

// ---------------------------------------------------------------------------
// fp32 -> fp8 e4m3 (OCP), RNE, input assumed in [0, 448).
// ---------------------------------------------------------------------------
__device__ __forceinline__ uint_t f32_to_e4m3(float f) {
  if (f < 0.015625f)                         // subnormal: m * 2^-9 (m=8 == min normal)
    return (uint_t)__float2int_rn(f * 512.0f);
  uint_t b = __builtin_bit_cast(uint_t, f);
  int e = (int)(b >> 23) - 127;
  uint_t m = b & 0x7FFFFFu;
  uint_t keep = m >> 20;
  uint_t rest = m & 0xFFFFFu;
  keep += (rest > 0x80000u) || (rest == 0x80000u && (keep & 1u));
  if (keep == 8u) { keep = 0u; e += 1; }
  if (e > 8) return 0x7Eu;                   // saturate 448
  return (uint_t)(((e + 7) << 3) | keep);
}

// ---------------------------------------------------------------------------
// Prep: pack filters to [chp][45][12] (rows 16B-aligned, b-contiguous).
// ---------------------------------------------------------------------------
__global__ void prep_kernel(const float* __restrict__ ft, const float* __restrict__ fn,
                            float* __restrict__ fT2)
{
  const int e = blockIdx.x * 256 + threadIdx.x;
  if (e < FT2_ELEMS) {
    const int chp = e / 540;
    const int rem = e - chp * 540;
    const int row = rem / 12;
    const int j = rem - row * 12;
    float v = 0.f;
    if (j < 11) {
      if (row < 33)      v = ft[chp * 363 + row * 11 + j];        // row = t*11+a
      else if (row < 44) v = fn[chp * 121 + (row - 33) * 11 + j]; // row-33 = a
    }
    fT2[e] = v;
  }
}

// ---------------------------------------------------------------------------
// Stage 1: thread = (ch-pair chp) x (16-px row). Block 128 = 8 rows x 16 chp.
// mode 0: x -> x1 (fp32). mode 1: xprev -> prevb (fp8 e4m3).
// ---------------------------------------------------------------------------
__global__ __launch_bounds__(128, 4) void feat_kernel(
    const float* __restrict__ xcur, const float* __restrict__ xprev,
    const float* __restrict__ fT2,
    float* __restrict__ out_x1, uchar_t* __restrict__ prevb)
{
  __shared__ float sPx[3 * 18 * 28];
  const int tid = threadIdx.x;
  const int chp = tid & 15;
  const int r = tid >> 4;              // 0..7
  const int j0 = blockIdx.x * 16;
  const int i0 = blockIdx.y * 8;
  const int i = i0 + r;
  const int mode = blockIdx.z;
  const float* __restrict__ xin = mode ? xprev : xcur;

  for (int e = tid; e < 3 * 18 * 26; e += 128) {
    const int t = e / 468;
    const int rem = e - t * 468;
    const int ri = rem / 26;
    const int ci = rem - ri * 26;
    sPx[(t * 18 + ri) * 28 + ci] = xin[((size_t)t * 394 + i0 + ri) * 394 + j0 + ci];
  }
  __syncthreads();

  const float* __restrict__ fbase = fT2 + chp * 540;

  float accT[16], accN[16];
#pragma unroll
  for (int p = 0; p < 16; ++p) { accT[p] = 0.f; accN[p] = 0.f; }

#pragma unroll
  for (int t = 0; t < 3; ++t) {
    for (int a = 0; a < 11; ++a) {
      const float* row = &sPx[(t * 18 + r + a) * 28];
      float wv[26];
#pragma unroll
      for (int k = 0; k < 6; ++k) {
        const f32x4 q = *(const f32x4*)(row + 4 * k);
        wv[4 * k + 0] = q[0]; wv[4 * k + 1] = q[1];
        wv[4 * k + 2] = q[2]; wv[4 * k + 3] = q[3];
      }
      wv[24] = row[24]; wv[25] = row[25];

      const float* fr = fbase + (t * 11 + a) * 12;
      const f32x4 fq0 = *(const f32x4*)(fr);
      const f32x4 fq1 = *(const f32x4*)(fr + 4);
      const f32x4 fq2 = *(const f32x4*)(fr + 8);
      float fv[12];
#pragma unroll
      for (int k = 0; k < 4; ++k) { fv[k] = fq0[k]; fv[4+k] = fq1[k]; fv[8+k] = fq2[k]; }
      float fv2[12];
      if (t == 2) {
        const float* fr2 = fbase + (33 + a) * 12;
        const f32x4 g0 = *(const f32x4*)(fr2);
        const f32x4 g1 = *(const f32x4*)(fr2 + 4);
        const f32x4 g2 = *(const f32x4*)(fr2 + 8);
#pragma unroll
        for (int k = 0; k < 4; ++k) { fv2[k] = g0[k]; fv2[4+k] = g1[k]; fv2[8+k] = g2[k]; }
      }

#pragma unroll
      for (int b = 0; b < 11; ++b) {
        const float fT = fv[b];
#pragma unroll
        for (int p = 0; p < 16; ++p) accT[p] = fmaf(wv[b + p], fT, accT[p]);
        if (t == 2) {
          const float fN = fv2[b];
#pragma unroll
          for (int p = 0; p < 16; ++p) accN[p] = fmaf(wv[b + p], fN, accN[p]);
        }
      }
    }
  }

  float o0[16], o1[16];
#pragma unroll
  for (int p = 0; p < 16; ++p) {
    const float vT = fmaxf(accT[p], 0.f) * 0.5f;   // temp: relu(conv)/2
    const float vN = fmaxf(accN[p], 0.f);
    float s = vT + vN;
    s += __shfl_xor(s, 1);  s += __shfl_xor(s, 2);
    s += __shfl_xor(s, 4);  s += __shfl_xor(s, 8);
    const float inv = 1.f / (s + EPSF);
    o0[p] = vT * inv;
    o1[p] = vN * inv;
  }

  if (mode == 0) {
#pragma unroll
    for (int q = 0; q < 4; ++q) {
      f32x4 v0 = {o0[4*q], o0[4*q+1], o0[4*q+2], o0[4*q+3]};
      f32x4 v1 = {o1[4*q], o1[4*q+1], o1[4*q+2], o1[4*q+3]};
      *(f32x4*)(out_x1 + (size_t)chp * 147456 + i * 384 + j0 + 4 * q) = v0;
      *(f32x4*)(out_x1 + (size_t)(chp + 16) * 147456 + i * 384 + j0 + 4 * q) = v1;
    }
  } else {
    uint4_t u0, u1;
#pragma unroll
    for (int q = 0; q < 4; ++q) {
      u0[q] = f32_to_e4m3(o0[4*q]) | (f32_to_e4m3(o0[4*q+1]) << 8) |
              (f32_to_e4m3(o0[4*q+2]) << 16) | (f32_to_e4m3(o0[4*q+3]) << 24);
      u1[q] = f32_to_e4m3(o1[4*q]) | (f32_to_e4m3(o1[4*q+1]) << 8) |
              (f32_to_e4m3(o1[4*q+2]) << 16) | (f32_to_e4m3(o1[4*q+3]) << 24);
    }
    *(uint4_t*)(prevb + ((size_t)chp * 385 + i) * PREVB_STRIDE + j0) = u0;
    *(uint4_t*)(prevb + ((size_t)(chp + 16) * 385 + i) * PREVB_STRIDE + j0) = u1;
  }
}

// ---------------------------------------------------------------------------
// Pack x1 (fp32, cropped) into filtb fp8 MFMA-A layout; coalesced 8B writes.
// thread e -> (rowr 5..366, xb 0..45, o 0..31).
// ---------------------------------------------------------------------------
__global__ __launch_bounds__(256) void pack_kernel(
    const float* __restrict__ x1, uchar_t* __restrict__ filtb)
{
  const int e = blockIdx.x * 256 + threadIdx.x;
  if (e >= 362 * 46 * 32) return;
  const int o = e & 31;
  const int q = e >> 5;
  const int xb = q % 46;
  const int rowr = q / 46 + 5;          // 5..366
  const int i = rowr + 6;               // 11..372
  const int j0 = 11 + xb * 8;
  const float* src = x1 + (size_t)o * 147456 + i * 384 + j0;
  uint_t w0 = 0, w1 = 0;
#pragma unroll
  for (int k = 0; k < 4; ++k) {
    w0 |= f32_to_e4m3((j0 + k     <= 372) ? src[k]     : 0.f) << (8 * k);
    w1 |= f32_to_e4m3((j0 + 4 + k <= 372) ? src[4 + k] : 0.f) << (8 * k);
  }
  uint2_t u = {w0, w1};
  *(uint2_t*)(filtb + (((size_t)(rowr * 48 + xb) * 32 + o) << 3)) = u;
}

// ---------------------------------------------------------------------------
// Stage 2: correlation via 16x16x32 fp8 MFMA.
//   out[o,c,dy,dx] = sum_{y,x} filt[o][y-dy_a][x] * prev[c][y+6*dy_b][x+dx]
//   M=(dy_a,o)=192, N=96: n = dyb*24+dx (dx 0..22, 23=pad), K=(y, x 0..383).
// Block 256 = 4 waves, ONE channel; wave w: Mt 3w..3w+2, all 6 Nt.
// A frag = 8B global dwordx2 (L2); B frag = 8B ds_read_b64 from shifted copy.
// ---------------------------------------------------------------------------
__global__ __launch_bounds__(256, 4) void corr_kernel(
    const uchar_t* __restrict__ filtb, const uchar_t* __restrict__ prevb,
    float* __restrict__ x2)
{
  __shared__ uint_t sB[SB_BYTES / 4];    // 13824 B

  const int tid = threadIdx.x;
  const int lane = tid & 63;
  const int w = tid >> 6;                // 0..3: Mt = 3w + m3
  const int h = lane >> 4;               // quad 0..3
  const int nl = lane & 15;

  const int ch = blockIdx.x >> 5;              // 0..31
  const int chunk = blockIdx.x & 31;           // 0..31; %8 == XCD
  const int y0 = (chunk * YMAX) / NCHUNKS;     // balanced 11-12 y-steps
  const int y1 = ((chunk + 1) * YMAX) / NCHUNKS;

  // Per-lane B-fragment byte offsets (Kt*32 added at use). All 8B-aligned.
  int boffB[6];
#pragma unroll
  for (int ntl = 0; ntl < 6; ++ntl) {
    const int n = ntl * 16 + nl;         // 0..95
    const int dyb = n / 24;
    const int dxr = n - 24 * dyb;
    const int dx = (dxr < 23) ? dxr : 22;      // pad lane reads valid data
    const int s = dx & 7;
    boffB[ntl] = dyb * SB_DYB_B + s * SB_COPY_B + (dx >> 3) * 8 + h * 8;
  }

  // Staging: 104 tasks: (dyb = t/26, g = t%26); each builds all 8 shifted
  // copies' bytes [16g,16g+16) from one 24B source window.
  const bool st_act = (tid < 104);
  const int sdyb = st_act ? (tid / 26) : 0;
  const int sg = tid - 26 * (st_act ? (tid / 26) : 0);
  const uchar_t* srcbase = prevb + ((size_t)(ch * 385 + 6 * sdyb)) * PREVB_STRIDE;
  uint_t* dstw = sB + sdyb * (SB_DYB_B / 4) + 4 * sg;

  f32x4 acc[3][6];
  const f32x4 zero = {0.f, 0.f, 0.f, 0.f};
#pragma unroll
  for (int a = 0; a < 3; ++a)
#pragma unroll
    for (int b = 0; b < 6; ++b) acc[a][b] = zero;

  for (int y = y0; y < y1; ++y) {
    __syncthreads();                     // prior compute done reading sB
    if (st_act) {
      const uint_t* sw = (const uint_t*)(srcbase + (size_t)y * PREVB_STRIDE) + 4 * sg;
      const uint4_t lo = *(const uint4_t*)(sw);
      const uint2_t hi = *(const uint2_t*)(sw + 4);
      const uint_t wd[6] = {lo.x, lo.y, lo.z, lo.w, hi.x, hi.y};
#pragma unroll
      for (int s = 0; s < 8; ++s) {
        const int off = s >> 2;
        const int b = (s & 3) * 8;
        uint4_t v;
        if (b == 0) {
          v = uint4_t{wd[off], wd[off + 1], wd[off + 2], wd[off + 3]};
        } else {
          v = uint4_t{(wd[off]     >> b) | (wd[off + 1] << (32 - b)),
                      (wd[off + 1] >> b) | (wd[off + 2] << (32 - b)),
                      (wd[off + 2] >> b) | (wd[off + 3] << (32 - b)),
                      (wd[off + 3] >> b) | (wd[off + 4] << (32 - b))};
        }
        *(uint4_t*)(dstw + s * (SB_COPY_B / 4)) = v;
      }
    }
    __syncthreads();                     // staging visible

    // Pipeline: B half-Kt double-buffered; A prefetched one full Kt ahead.
    long Af[3], Afn[3], Bf[3], Bfn[3];
    const uchar_t* aptr[3];
#pragma unroll
    for (int m3 = 0; m3 < 3; ++m3) {
      const int Mt = 3 * w + m3;
      const int row = y - (Mt >> 1) + 5;               // in [0,371]
      const int o = ((Mt & 1) << 4) + nl;
      aptr[m3] = filtb + (((size_t)(row * 48 + h) * 32 + o) << 3);
      Af[m3] = *(const long*)(aptr[m3]);
    }
#pragma unroll
    for (int ntl = 0; ntl < 3; ++ntl)
      Bf[ntl] = *(const long*)((const char*)sB + boffB[ntl]);

#pragma unroll
    for (int Kt = 0; Kt < 12; ++Kt) {
      // prefetch B half1 (this Kt) and A (next Kt); Kt stride: 4*32*8 = 1024B
#pragma unroll
      for (int ntl = 0; ntl < 3; ++ntl)
        Bfn[ntl] = *(const long*)((const char*)sB + boffB[3 + ntl] + (Kt << 5));
      const int Ktn = (Kt < 11) ? Kt + 1 : 11;
#pragma unroll
      for (int m3 = 0; m3 < 3; ++m3)
        Afn[m3] = *(const long*)(aptr[m3] + (Ktn << 10));
      // half0: A(Kt) x B(Kt, ntl 0..2)
#pragma unroll
      for (int ntl = 0; ntl < 3; ++ntl)
#pragma unroll
        for (int m3 = 0; m3 < 3; ++m3)
          acc[m3][ntl] = __builtin_amdgcn_mfma_f32_16x16x32_fp8_fp8(
              Af[m3], Bf[ntl], acc[m3][ntl], 0, 0, 0);
      // prefetch B half0 (next Kt)
      const int Kt2 = (Kt < 11) ? Kt + 1 : 11;
#pragma unroll
      for (int ntl = 0; ntl < 3; ++ntl)
        Bf[ntl] = *(const long*)((const char*)sB + boffB[ntl] + (Kt2 << 5));
      // half1: A(Kt) x B(Kt, ntl 3..5)
#pragma unroll
      for (int ntl = 0; ntl < 3; ++ntl)
#pragma unroll
        for (int m3 = 0; m3 < 3; ++m3)
          acc[m3][3 + ntl] = __builtin_amdgcn_mfma_f32_16x16x32_fp8_fp8(
              Af[m3], Bfn[ntl], acc[m3][3 + ntl], 0, 0, 0);
      // rotate A
#pragma unroll
      for (int m3 = 0; m3 < 3; ++m3) Af[m3] = Afn[m3];
    }
  }

  // Epilogue: scale partials, atomically accumulate into x2[o][c][dy][dx].
#pragma unroll
  for (int ntl = 0; ntl < 6; ++ntl) {
    const int n = ntl * 16 + nl;
    const int dyb = n / 24;
    const int dxr = n - 24 * dyb;
    if (dxr < 23) {
#pragma unroll
      for (int m3 = 0; m3 < 3; ++m3) {
        const int Mt = 3 * w + m3;
#pragma unroll
        for (int r = 0; r < 4; ++r) {
          const int m = Mt * 16 + h * 4 + r; // C/D: row=(lane>>4)*4+reg, col=lane&15
          const int o = m & 31;
          const int dy = (m >> 5) + 6 * dyb;
          if (dy <= 22)
            atomicAdd(&x2[((o * 32 + ch) * 23 + dy) * 23 + dxr],
                      acc[m3][ntl][r] * INV_AREA);
        }
      }
    }
  }
}

// ---------------------------------------------------------------------------
extern "C" void kernel_launch(void* const* d_in, const int* in_sizes, int n_in,
                              void* d_out, int out_size, void* d_ws, size_t ws_size,
                              hipStream_t stream)
{
  const float* x     = (const float*)d_in[0];   // [3][394][394]
  const float* xprev = (const float*)d_in[1];
  const float* ft    = (const float*)d_in[2];   // [16][3][11][11]
  const float* fn    = (const float*)d_in[3];   // [16][1][11][11]
  float* out = (float*)d_out;

  uchar_t* filtb = (uchar_t*)d_ws;
  uchar_t* prevb = filtb + FILTB_BYTES;
  float* fT2 = (float*)(prevb + PREVB_BYTES);

  // Zero packed buffers (zero padding) and the x2 accumulator.
  hipMemsetAsync(d_ws, 0, ZERO_BYTES, stream);
  hipMemsetAsync(out + X1_N, 0, (size_t)X2_N * sizeof(float), stream);

  prep_kernel<<<dim3((FT2_ELEMS + 255) / 256), 256, 0, stream>>>(ft, fn, fT2);
  feat_kernel<<<dim3(24, 48, 2), 128, 0, stream>>>(x, xprev, fT2, out, prevb);
  pack_kernel<<<dim3((362 * 46 * 32 + 255) / 256), 256, 0, stream>>>(out, filtb);
  corr_kernel<<<dim3(32 * NCHUNKS), 256, 0, stream>>>(filtb, prevb, out + X1_N);
}

// Round 10
// 346.612 us; speedup vs baseline: 1.0750x; 1.0750x over previous
//
#include <hip/hip_runtime.h>
#include <hip/hip_bf16.h>

// Net_22625887715641: fused conv-feats + channel-normalize + 32x32 normalized
// cross-correlation (23x23 shifts, 362x362 templates).
//
// R10 vs R9 (corr 230us, fp8@16x16 neutral: same MFMA rate as bf16, still
// spilled at (256,4), A vmcnt stall every Kt):
//  - corr: mfma_f32_32x32x16_fp8_fp8, 384-thr/6-wave blocks; wave w = dy_a
//    (A row wave-uniform), 3 N-tiles of 32/wave. acc 48 + operands ~16 +
//    misc ~28 = ~92 regs -> no spill, 5 waves/SIMD, 3 blocks/CU.
//  - Half the MFMA instructions at the best-measured shape rate (32x32:
//    2190-2495 TF ubench vs 2075 for 16x16). Floor ~76us.
//  - A prefetch 2 Kt deep (~200cyc ~ L2 latency); B ds_read_b64 <=2-way banks.
//  - Staging: R7-style register prefetch of next-y restored.
//  - feat/pack/prep unchanged from R9.

typedef unsigned short ushort_t;
typedef unsigned int uint_t;
typedef unsigned char uchar_t;
typedef __attribute__((ext_vector_type(4))) float f32x4;
typedef __attribute__((ext_vector_type(16))) float f32x16;
typedef __attribute__((ext_vector_type(4))) uint_t uint4_t;
typedef __attribute__((ext_vector_type(2))) uint_t uint2_t;

#define EPSF 2.2204460492503131e-16f
#define X1_N (32*384*384)
#define X2_N (32*32*23*23)

// filtb: fp8 [372 rows][48 xb][32 o][8 j]; row = yf+5 (data rows 5..366)
#define FILTB_BYTES (372*48*32*8)
// prevb: fp8 [32 c][385 rows][432 x]; data rows 0..383 cols 0..383; zeros else
#define PREVB_STRIDE 432
#define PREVB_BYTES (32*385*PREVB_STRIDE)
#define ZERO_BYTES ((size_t)FILTB_BYTES + PREVB_BYTES)
// fT2: fp32 [16 chp][45 rows][12] after prevb
#define FT2_ELEMS (16*45*12)

#define YMAX 367            // y-steps 0..366
#define NCHUNKS 24          // balanced: chunk c covers [c*367/24,(c+1)*367/24)
#define INV_AREA (1.0f/131044.0f)

// sB bytes: [dyb 4][copy 8][432]; copy stride 432 (16-mult, 48B bank stagger)
#define SB_COPY_B 432
#define SB_DYB_B  (8*SB_COPY_B)     // 3456
#define SB_BYTES  (4*SB_DYB_B)      // 13824 B

// ---------------------------------------------------------------------------
// fp32 -> fp8 e4m3 (OCP), RNE, input assumed in [0, 448).
// ---------------------------------------------------------------------------
__device__ __forceinline__ uint_t f32_to_e4m3(float f) {
  if (f < 0.015625f)                         // subnormal: m * 2^-9
    return (uint_t)__float2int_rn(f * 512.0f);
  uint_t b = __builtin_bit_cast(uint_t, f);
  int e = (int)(b >> 23) - 127;
  uint_t m = b & 0x7FFFFFu;
  uint_t keep = m >> 20;
  uint_t rest = m & 0xFFFFFu;
  keep += (rest > 0x80000u) || (rest == 0x80000u && (keep & 1u));
  if (keep == 8u) { keep = 0u; e += 1; }
  if (e > 8) return 0x7Eu;                   // saturate 448
  return (uint_t)(((e + 7) << 3) | keep);
}

// ---------------------------------------------------------------------------
// Prep: pack filters to [chp][45][12] (rows 16B-aligned, b-contiguous).
// ---------------------------------------------------------------------------
__global__ void prep_kernel(const float* __restrict__ ft, const float* __restrict__ fn,
                            float* __restrict__ fT2)
{
  const int e = blockIdx.x * 256 + threadIdx.x;
  if (e < FT2_ELEMS) {
    const int chp = e / 540;
    const int rem = e - chp * 540;
    const int row = rem / 12;
    const int j = rem - row * 12;
    float v = 0.f;
    if (j < 11) {
      if (row < 33)      v = ft[chp * 363 + row * 11 + j];        // row = t*11+a
      else if (row < 44) v = fn[chp * 121 + (row - 33) * 11 + j]; // row-33 = a
    }
    fT2[e] = v;
  }
}

// ---------------------------------------------------------------------------
// Stage 1: thread = (ch-pair chp) x (16-px row). Block 128 = 8 rows x 16 chp.
// mode 0: x -> x1 (fp32). mode 1: xprev -> prevb (fp8 e4m3).
// ---------------------------------------------------------------------------
__global__ __launch_bounds__(128, 4) void feat_kernel(
    const float* __restrict__ xcur, const float* __restrict__ xprev,
    const float* __restrict__ fT2,
    float* __restrict__ out_x1, uchar_t* __restrict__ prevb)
{
  __shared__ float sPx[3 * 18 * 28];
  const int tid = threadIdx.x;
  const int chp = tid & 15;
  const int r = tid >> 4;              // 0..7
  const int j0 = blockIdx.x * 16;
  const int i0 = blockIdx.y * 8;
  const int i = i0 + r;
  const int mode = blockIdx.z;
  const float* __restrict__ xin = mode ? xprev : xcur;

  for (int e = tid; e < 3 * 18 * 26; e += 128) {
    const int t = e / 468;
    const int rem = e - t * 468;
    const int ri = rem / 26;
    const int ci = rem - ri * 26;
    sPx[(t * 18 + ri) * 28 + ci] = xin[((size_t)t * 394 + i0 + ri) * 394 + j0 + ci];
  }
  __syncthreads();

  const float* __restrict__ fbase = fT2 + chp * 540;

  float accT[16], accN[16];
#pragma unroll
  for (int p = 0; p < 16; ++p) { accT[p] = 0.f; accN[p] = 0.f; }

#pragma unroll
  for (int t = 0; t < 3; ++t) {
    for (int a = 0; a < 11; ++a) {
      const float* row = &sPx[(t * 18 + r + a) * 28];
      float wv[26];
#pragma unroll
      for (int k = 0; k < 6; ++k) {
        const f32x4 q = *(const f32x4*)(row + 4 * k);
        wv[4 * k + 0] = q[0]; wv[4 * k + 1] = q[1];
        wv[4 * k + 2] = q[2]; wv[4 * k + 3] = q[3];
      }
      wv[24] = row[24]; wv[25] = row[25];

      const float* fr = fbase + (t * 11 + a) * 12;
      const f32x4 fq0 = *(const f32x4*)(fr);
      const f32x4 fq1 = *(const f32x4*)(fr + 4);
      const f32x4 fq2 = *(const f32x4*)(fr + 8);
      float fv[12];
#pragma unroll
      for (int k = 0; k < 4; ++k) { fv[k] = fq0[k]; fv[4+k] = fq1[k]; fv[8+k] = fq2[k]; }
      float fv2[12];
      if (t == 2) {
        const float* fr2 = fbase + (33 + a) * 12;
        const f32x4 g0 = *(const f32x4*)(fr2);
        const f32x4 g1 = *(const f32x4*)(fr2 + 4);
        const f32x4 g2 = *(const f32x4*)(fr2 + 8);
#pragma unroll
        for (int k = 0; k < 4; ++k) { fv2[k] = g0[k]; fv2[4+k] = g1[k]; fv2[8+k] = g2[k]; }
      }

#pragma unroll
      for (int b = 0; b < 11; ++b) {
        const float fT = fv[b];
#pragma unroll
        for (int p = 0; p < 16; ++p) accT[p] = fmaf(wv[b + p], fT, accT[p]);
        if (t == 2) {
          const float fN = fv2[b];
#pragma unroll
          for (int p = 0; p < 16; ++p) accN[p] = fmaf(wv[b + p], fN, accN[p]);
        }
      }
    }
  }

  float o0[16], o1[16];
#pragma unroll
  for (int p = 0; p < 16; ++p) {
    const float vT = fmaxf(accT[p], 0.f) * 0.5f;   // temp: relu(conv)/2
    const float vN = fmaxf(accN[p], 0.f);
    float s = vT + vN;
    s += __shfl_xor(s, 1);  s += __shfl_xor(s, 2);
    s += __shfl_xor(s, 4);  s += __shfl_xor(s, 8);
    const float inv = 1.f / (s + EPSF);
    o0[p] = vT * inv;
    o1[p] = vN * inv;
  }

  if (mode == 0) {
#pragma unroll
    for (int q = 0; q < 4; ++q) {
      f32x4 v0 = {o0[4*q], o0[4*q+1], o0[4*q+2], o0[4*q+3]};
      f32x4 v1 = {o1[4*q], o1[4*q+1], o1[4*q+2], o1[4*q+3]};
      *(f32x4*)(out_x1 + (size_t)chp * 147456 + i * 384 + j0 + 4 * q) = v0;
      *(f32x4*)(out_x1 + (size_t)(chp + 16) * 147456 + i * 384 + j0 + 4 * q) = v1;
    }
  } else {
    uint4_t u0, u1;
#pragma unroll
    for (int q = 0; q < 4; ++q) {
      u0[q] = f32_to_e4m3(o0[4*q]) | (f32_to_e4m3(o0[4*q+1]) << 8) |
              (f32_to_e4m3(o0[4*q+2]) << 16) | (f32_to_e4m3(o0[4*q+3]) << 24);
      u1[q] = f32_to_e4m3(o1[4*q]) | (f32_to_e4m3(o1[4*q+1]) << 8) |
              (f32_to_e4m3(o1[4*q+2]) << 16) | (f32_to_e4m3(o1[4*q+3]) << 24);
    }
    *(uint4_t*)(prevb + ((size_t)chp * 385 + i) * PREVB_STRIDE + j0) = u0;
    *(uint4_t*)(prevb + ((size_t)(chp + 16) * 385 + i) * PREVB_STRIDE + j0) = u1;
  }
}

// ---------------------------------------------------------------------------
// Pack x1 (fp32, cropped) into filtb fp8 MFMA-A layout; coalesced 8B writes.
// ---------------------------------------------------------------------------
__global__ __launch_bounds__(256) void pack_kernel(
    const float* __restrict__ x1, uchar_t* __restrict__ filtb)
{
  const int e = blockIdx.x * 256 + threadIdx.x;
  if (e >= 362 * 46 * 32) return;
  const int o = e & 31;
  const int q = e >> 5;
  const int xb = q % 46;
  const int rowr = q / 46 + 5;          // 5..366
  const int i = rowr + 6;               // 11..372
  const int j0 = 11 + xb * 8;
  const float* src = x1 + (size_t)o * 147456 + i * 384 + j0;
  uint_t w0 = 0, w1 = 0;
#pragma unroll
  for (int k = 0; k < 4; ++k) {
    w0 |= f32_to_e4m3((j0 + k     <= 372) ? src[k]     : 0.f) << (8 * k);
    w1 |= f32_to_e4m3((j0 + 4 + k <= 372) ? src[4 + k] : 0.f) << (8 * k);
  }
  uint2_t u = {w0, w1};
  *(uint2_t*)(filtb + (((size_t)(rowr * 48 + xb) * 32 + o) << 3)) = u;
}

// ---------------------------------------------------------------------------
// Stage 2: correlation via 32x32x16 fp8 MFMA.
//   out[o,c,dy,dx] = sum_{y,x} filt[o][y-dy_a][x] * prev[c][y+6*dy_b][x+dx]
//   M=192=(dy_a 6)x(o 32); N=96: n = dyb*24+dx (dx 0..22, 23=pad); K=(y, x).
// Block 384 thr = 6 waves, ONE channel; wave w = dy_a w, all 3 N-tiles of 32.
// A-operand row = y-w+5 is WAVE-UNIFORM -> one coalesced 8B load/lane/Kt.
// Operand map (32x32x16): m/n = lane&31, k = (lane>>5)*8 + j.
// C/D map: col = lane&31, row = (reg&3)+8*(reg>>2)+4*(lane>>5).
// ---------------------------------------------------------------------------
__global__ __launch_bounds__(384, 4) void corr_kernel(
    const uchar_t* __restrict__ filtb, const uchar_t* __restrict__ prevb,
    float* __restrict__ x2)
{
  __shared__ uint_t sB[SB_BYTES / 4];    // 13824 B

  const int tid = threadIdx.x;
  const int lane = tid & 63;
  const int w = tid >> 6;                // 0..5 = dy_a
  const int kg = lane >> 5;              // k-group 0..1
  const int nn = lane & 31;              // n (or o) within tile

  const int ch = blockIdx.x / NCHUNKS;         // 0..31
  const int chunk = blockIdx.x % NCHUNKS;      // 0..23; %8 == XCD
  const int y0 = (chunk * YMAX) / NCHUNKS;     // balanced 15-16 y-steps
  const int y1 = ((chunk + 1) * YMAX) / NCHUNKS;

  // Per-lane B-fragment byte offsets (Kt*16 added at use). All 8B-aligned.
  int boffB[3];
#pragma unroll
  for (int nt = 0; nt < 3; ++nt) {
    const int n = nt * 32 + nn;          // 0..95
    const int dyb = n / 24;
    const int dxr = n - 24 * dyb;
    const int dx = (dxr < 23) ? dxr : 22;      // pad lane reads valid data
    const int s = dx & 7;
    boffB[nt] = dyb * SB_DYB_B + s * SB_COPY_B + (dx >> 3) * 8 + kg * 8;
  }

  // Staging: 104 tasks (dyb = t/26, 16B group g = t%26); 24B src window each.
  const bool st_act = (tid < 104);
  const int sdyb = st_act ? (tid / 26) : 0;
  const int sg = tid - 26 * (st_act ? (tid / 26) : 0);
  const uchar_t* srcbase = prevb + ((size_t)(ch * 385 + 6 * sdyb)) * PREVB_STRIDE;
  uint_t* dstw = sB + sdyb * (SB_DYB_B / 4) + 4 * sg;

  f32x16 acc[3];
#pragma unroll
  for (int nt = 0; nt < 3; ++nt)
#pragma unroll
    for (int r = 0; r < 16; ++r) acc[nt][r] = 0.f;

  // A base for y0: row = y - w + 5; per-lane offset kg*256 + nn*8; y-stride 12288.
  const uchar_t* aptr = filtb + (size_t)(y0 - w + 5) * 12288 + kg * 256 + nn * 8;

  // preload staging regs for y0
  uint_t st0, st1, st2, st3, st4, st5;
  if (st_act) {
    const uint_t* sw = (const uint_t*)(srcbase + (size_t)y0 * PREVB_STRIDE) + 4 * sg;
    const uint4_t lo = *(const uint4_t*)(sw);
    const uint2_t hi = *(const uint2_t*)(sw + 4);
    st0 = lo.x; st1 = lo.y; st2 = lo.z; st3 = lo.w; st4 = hi.x; st5 = hi.y;
  }

  for (int y = y0; y < y1; ++y) {
    __syncthreads();                     // prior compute done reading sB
    if (st_act) {
      const uint_t wd[6] = {st0, st1, st2, st3, st4, st5};
#pragma unroll
      for (int s = 0; s < 8; ++s) {
        const int off = s >> 2;
        const int b = (s & 3) * 8;
        uint4_t v;
        if (b == 0) {
          v = uint4_t{wd[off], wd[off + 1], wd[off + 2], wd[off + 3]};
        } else {
          v = uint4_t{(wd[off]     >> b) | (wd[off + 1] << (32 - b)),
                      (wd[off + 1] >> b) | (wd[off + 2] << (32 - b)),
                      (wd[off + 2] >> b) | (wd[off + 3] << (32 - b)),
                      (wd[off + 3] >> b) | (wd[off + 4] << (32 - b))};
        }
        *(uint4_t*)(dstw + s * (SB_COPY_B / 4)) = v;
      }
    }
    __syncthreads();                     // staging visible

    if (st_act && (y + 1 < y1)) {        // register-prefetch next y
      const uint_t* sw = (const uint_t*)(srcbase + (size_t)(y + 1) * PREVB_STRIDE) + 4 * sg;
      const uint4_t lo = *(const uint4_t*)(sw);
      const uint2_t hi = *(const uint2_t*)(sw + 4);
      st0 = lo.x; st1 = lo.y; st2 = lo.z; st3 = lo.w; st4 = hi.x; st5 = hi.y;
    }

    // K-loop: 24 Kt16 steps; A prefetched 2 deep, B 1 deep.
    long Af0, Af1, Af2, Bf[3], Bfn[3];
    Af0 = *(const long*)(aptr);                       // Kt 0 (stride 512B/Kt)
    Af1 = *(const long*)(aptr + 512);                 // Kt 1
#pragma unroll
    for (int nt = 0; nt < 3; ++nt)
      Bf[nt] = *(const long*)((const char*)sB + boffB[nt]);

#pragma unroll
    for (int Kt = 0; Kt < 24; ++Kt) {
      const int Kta = (Kt + 2 < 24) ? Kt + 2 : 23;
      Af2 = *(const long*)(aptr + (Kta << 9));
      const int Ktb = (Kt + 1 < 24) ? Kt + 1 : 23;
#pragma unroll
      for (int nt = 0; nt < 3; ++nt)
        Bfn[nt] = *(const long*)((const char*)sB + boffB[nt] + (Ktb << 4));
#pragma unroll
      for (int nt = 0; nt < 3; ++nt)
        acc[nt] = __builtin_amdgcn_mfma_f32_32x32x16_fp8_fp8(
            Af0, Bf[nt], acc[nt], 0, 0, 0);
      Af0 = Af1; Af1 = Af2;
#pragma unroll
      for (int nt = 0; nt < 3; ++nt) Bf[nt] = Bfn[nt];
    }
    aptr += 12288;                       // next y: row += 1
  }

  // Epilogue: scale partials, atomically accumulate into x2[o][c][dy][dx].
#pragma unroll
  for (int nt = 0; nt < 3; ++nt) {
    const int n = nt * 32 + nn;
    const int dyb = n / 24;
    const int dxr = n - 24 * dyb;
    if (dxr < 23) {
      const int dy = w + 6 * dyb;
      if (dy <= 22) {
#pragma unroll
        for (int r = 0; r < 16; ++r) {
          const int o = (r & 3) + 8 * (r >> 2) + 4 * kg;   // C/D row
          atomicAdd(&x2[((o * 32 + ch) * 23 + dy) * 23 + dxr],
                    acc[nt][r] * INV_AREA);
        }
      }
    }
  }
}

// ---------------------------------------------------------------------------
extern "C" void kernel_launch(void* const* d_in, const int* in_sizes, int n_in,
                              void* d_out, int out_size, void* d_ws, size_t ws_size,
                              hipStream_t stream)
{
  const float* x     = (const float*)d_in[0];   // [3][394][394]
  const float* xprev = (const float*)d_in[1];
  const float* ft    = (const float*)d_in[2];   // [16][3][11][11]
  const float* fn    = (const float*)d_in[3];   // [16][1][11][11]
  float* out = (float*)d_out;

  uchar_t* filtb = (uchar_t*)d_ws;
  uchar_t* prevb = filtb + FILTB_BYTES;
  float* fT2 = (float*)(prevb + PREVB_BYTES);

  // Zero packed buffers (zero padding) and the x2 accumulator.
  hipMemsetAsync(d_ws, 0, ZERO_BYTES, stream);
  hipMemsetAsync(out + X1_N, 0, (size_t)X2_N * sizeof(float), stream);

  prep_kernel<<<dim3((FT2_ELEMS + 255) / 256), 256, 0, stream>>>(ft, fn, fT2);
  feat_kernel<<<dim3(24, 48, 2), 128, 0, stream>>>(x, xprev, fT2, out, prevb);
  pack_kernel<<<dim3((362 * 46 * 32 + 255) / 256), 256, 0, stream>>>(out, filtb);
  corr_kernel<<<dim3(32 * NCHUNKS), 384, 0, stream>>>(filtb, prevb, out + X1_N);
}